// Round 8
// baseline (47.692 us; speedup 1.0000x reference)
//
#include <hip/hip_runtime.h>

// ViT patch-embed. out[b,0,e]=cls[e]+pos[0,e]; out[b,n+1,e]=sum_k patch[b,n,k]W[e,k]+pos[n+1,e]
// B=1024, 64 patches K=48 (pad 64), E=768. Output 204.5 MB f32; fill-demonstrated
// write ceiling 6.9 TB/s -> ~30.5us floor.
// Ledger: R4 NT stores -11.5us. R6 swapped-operand scatter -12us. R5 scattered
// 64B stores == R7 LDS-staged full-line stores == 46.5-46.8us -> store pattern
// exonerated. R8 theory: coarse phase overlap + per-block W-convert redundancy.
//   prep kernel: W -> bf16 in d_ws (74 KB) + all cls rows.
//   main kernel: 8192 light blocks (256 thr, 4/CU), per block one (batch,
//   16-patch tile, 384-embed half): 3KB stage, bf16 W frags (no cvt), 12 MFMA.

#define BATCH   1024
#define EMBED   768
#define NPATCH  64
#define SEQ     65
#define OUTB    (SEQ * EMBED)   // 49920
#define WELEMS  (EMBED * 48)    // 36864

typedef __attribute__((ext_vector_type(8))) short bf16x8;   // 8 bf16 (4 VGPRs)
typedef __attribute__((ext_vector_type(4))) float f32x4;    // MFMA acc / 16B ld-st

__device__ __forceinline__ short f2bf(float f) {
    union { float f; unsigned u; } v; v.f = f;
    unsigned r = v.u + 0x7FFFu + ((v.u >> 16) & 1u);   // RNE
    return (short)(r >> 16);
}

// ---------------------------------------------------------------------------
// Prep: blocks 0..17 convert W (36864 f32 -> bf16, 8/thread) into d_ws;
//       blocks 18..1041 write cls row for batch b = bid-18.
// ---------------------------------------------------------------------------
__global__ __launch_bounds__(256) void prep_kernel(const float* __restrict__ W,
                                                   const float* __restrict__ cls,
                                                   const float* __restrict__ pos,
                                                   short* __restrict__ w16,
                                                   float* __restrict__ out) {
    const int tid = threadIdx.x;
    const int bid = blockIdx.x;
    if (bid < 18) {
        const int i = (bid * 256 + tid) * 8;     // f32 index, 8 per thread
        float4 u0 = *(const float4*)(W + i);
        float4 u1 = *(const float4*)(W + i + 4);
        bf16x8 v;
        v[0] = f2bf(u0.x); v[1] = f2bf(u0.y); v[2] = f2bf(u0.z); v[3] = f2bf(u0.w);
        v[4] = f2bf(u1.x); v[5] = f2bf(u1.y); v[6] = f2bf(u1.z); v[7] = f2bf(u1.w);
        *(bf16x8*)(w16 + i) = v;
    } else {
        const int b = bid - 18;
        if (tid < 192) {
            f32x4 cv = ((const f32x4*)cls)[tid];
            f32x4 pv = ((const f32x4*)pos)[tid];
            ((f32x4*)out)[(size_t)b * (OUTB / 4) + tid] = cv + pv;
        }
    }
}

// ---------------------------------------------------------------------------
// Main: grid 8192. bid -> b = bid>>3; sub = bid&7: mt = sub>>1 (16-patch tile),
// eh = sub&1 (384-embed half). 4 waves; wave owns 96 embeds (6 N-tiles).
// A-frag = patch rows (LDS, XOR-swizzled 16B chunks), B-frag = W cols (bf16 ws).
// v_mfma_f32_16x16x32_bf16: D lane -> col e (l&15), row n = (l>>4)*4 + reg.
// ---------------------------------------------------------------------------
__global__ __launch_bounds__(256, 4) void patch_embed_main(const float* __restrict__ x,
                                                           const short* __restrict__ w16,
                                                           const float* __restrict__ pos,
                                                           float* __restrict__ out) {
    __shared__ short A[16 * 64];   // 2 KB

    const int tid  = threadIdx.x;
    const int lane = tid & 63;
    const int wave = tid >> 6;     // 0..3
    const int lr   = lane & 15;
    const int lg   = lane >> 4;    // 0..3
    const int bid  = blockIdx.x;
    const int b    = bid >> 3;
    const int sub  = bid & 7;
    const int mt   = sub >> 1;     // 0..3: 16-patch M-tile
    const int eh   = sub & 1;      // embed half
    const int ebase = eh * 384 + wave * 96;

    // ---- stage 16 patches (n = mt*16 + row) -> A[16][64], swizzled chunks ----
    if (tid < 128) {
        const int row = tid >> 3;          // local patch row 0..15
        const int kb  = tid & 7;
        short* dst = &A[row * 64 + ((kb ^ (row & 7)) * 8)];
        bf16x8 v = {0, 0, 0, 0, 0, 0, 0, 0};
        if (kb < 6) {   // k = c*16 + ph*4 + pw
            const int n   = mt * 16 + row;
            const int c   = kb >> 1;
            const int ph0 = (kb & 1) * 2;
            const int gr = n >> 3, gc = n & 7;
            const float* src = x + (size_t)b * 3072 + c * 1024 + (gr * 4 + ph0) * 32 + gc * 4;
            float4 u0 = *(const float4*)src;
            float4 u1 = *(const float4*)(src + 32);
            v[0] = f2bf(u0.x); v[1] = f2bf(u0.y); v[2] = f2bf(u0.z); v[3] = f2bf(u0.w);
            v[4] = f2bf(u1.x); v[5] = f2bf(u1.y); v[6] = f2bf(u1.z); v[7] = f2bf(u1.w);
        }
        *(bf16x8*)dst = v;
    }

    // ---- W fragments (B-operand) from bf16 ws: bw[6][2], no conversion ----
    // lane holds W row (ebase + nt*16 + lr), k = kk*32 + lg*8 + j; rows are 96 B.
    bf16x8 bw[6][2];
    #pragma unroll
    for (int nt = 0; nt < 6; ++nt) {
        const short* wrow = w16 + (ebase + nt * 16 + lr) * 48;
        bw[nt][0] = *(const bf16x8*)(wrow + lg * 8);           // k0 = 0,8,16,24
        const int k1 = 32 + lg * 8;                            // 32,40,48,56
        bf16x8 f = {0, 0, 0, 0, 0, 0, 0, 0};
        if (k1 < 48) f = *(const bf16x8*)(wrow + k1);
        bw[nt][1] = f;
    }

    __syncthreads();

    // ---- one M-tile: 2 LDS reads, 12 MFMA, scalar epilogue (R5-proven) ----
    bf16x8 a0 = *(const bf16x8*)&A[lr * 64 + ((lg ^ (lr & 7)) * 8)];         // k 0..31
    bf16x8 a1 = *(const bf16x8*)&A[lr * 64 + (((4 + lg) ^ (lr & 7)) * 8)];   // k 32..63

    f32x4 acc[6];
    const f32x4 zero = {0.f, 0.f, 0.f, 0.f};
    #pragma unroll
    for (int nt = 0; nt < 6; ++nt)
        acc[nt] = __builtin_amdgcn_mfma_f32_16x16x32_bf16(a0, bw[nt][0], zero, 0, 0, 0);
    #pragma unroll
    for (int nt = 0; nt < 6; ++nt)
        acc[nt] = __builtin_amdgcn_mfma_f32_16x16x32_bf16(a1, bw[nt][1], acc[nt], 0, 0, 0);

    // D: lane holds col (ebase + nt*16 + lr), rows n = mt*16 + lg*4 + j
    #pragma unroll
    for (int j = 0; j < 4; ++j) {
        const int n = mt * 16 + lg * 4 + j;
        const float* prow = pos + (size_t)(n + 1) * EMBED + ebase + lr;
        float* orow = out + (size_t)b * OUTB + (size_t)(n + 1) * EMBED + ebase + lr;
        #pragma unroll
        for (int nt = 0; nt < 6; ++nt)
            orow[nt * 16] = acc[nt][j] + prow[nt * 16];
    }
}

// ---------------------------------------------------------------------------
// d_ws usage: 36864 bf16 = 73,728 B for converted W (assumed <= ws_size).
// ---------------------------------------------------------------------------
extern "C" void kernel_launch(void* const* d_in, const int* in_sizes, int n_in,
                              void* d_out, int out_size, void* d_ws, size_t ws_size,
                              hipStream_t stream) {
    const float* x   = (const float*)d_in[0];
    const float* W   = (const float*)d_in[1];
    const float* cls = (const float*)d_in[2];
    const float* pos = (const float*)d_in[3];
    float* out = (float*)d_out;
    short* w16 = (short*)d_ws;

    hipLaunchKernelGGL(prep_kernel, dim3(18 + BATCH), dim3(256), 0, stream,
                       W, cls, pos, w16, out);
    hipLaunchKernelGGL(patch_embed_main, dim3(BATCH * 8), dim3(256), 0, stream,
                       x, w16, pos, out);
}

// Round 9
// 46.218 us; speedup vs baseline: 1.0319x; 1.0319x over previous
//
#include <hip/hip_runtime.h>

// ViT patch-embed. out[b,0,e]=cls[e]+pos[0,e]; out[b,n+1,e]=sum_k patch[b,n,k]W[e,k]+pos[n+1,e]
// B=1024, 64 patches K=48 (pad 64), E=768. Output 204.5 MB f32.
// Ledger: R4 NT stores -11.5us. R6 16-row-scatter x4 stores -12us. R5 scalar
// scatter == R7 LDS-staged full-line == R8 4-blocks/CU == 46.5-47.7us.
// R9 theory: store duty cycle -- every prior epilogue serialized pos-L2-load
// (~300cyc) -> add -> store. Here: pos prefetched to regs BEFORE the MFMAs,
// stores issue unblocked; 4 tiles/block amortize prologue; no inter-tile
// barriers; 2048 blocks x 256 thr (4/CU).

#define BATCH   1024
#define EMBED   768
#define NPATCH  64
#define SEQ     65
#define OUTB    (SEQ * EMBED)   // 49920
#define WELEMS  (EMBED * 48)    // 36864

typedef __attribute__((ext_vector_type(8))) short bf16x8;   // 8 bf16 (4 VGPRs)
typedef __attribute__((ext_vector_type(4))) float f32x4;    // MFMA acc / 16B ld-st

__device__ __forceinline__ short f2bf(float f) {
    union { float f; unsigned u; } v; v.f = f;
    unsigned r = v.u + 0x7FFFu + ((v.u >> 16) & 1u);   // RNE
    return (short)(r >> 16);
}

// ---------------------------------------------------------------------------
// Prep: blocks 0..17 convert W (36864 f32 -> bf16, 8/thread) into d_ws;
//       blocks 18..1041 write cls row for batch b = bid-18.
// ---------------------------------------------------------------------------
__global__ __launch_bounds__(256) void prep_kernel(const float* __restrict__ W,
                                                   const float* __restrict__ cls,
                                                   const float* __restrict__ pos,
                                                   short* __restrict__ w16,
                                                   float* __restrict__ out) {
    const int tid = threadIdx.x;
    const int bid = blockIdx.x;
    if (bid < 18) {
        const int i = (bid * 256 + tid) * 8;     // f32 index, 8 per thread
        float4 u0 = *(const float4*)(W + i);
        float4 u1 = *(const float4*)(W + i + 4);
        bf16x8 v;
        v[0] = f2bf(u0.x); v[1] = f2bf(u0.y); v[2] = f2bf(u0.z); v[3] = f2bf(u0.w);
        v[4] = f2bf(u1.x); v[5] = f2bf(u1.y); v[6] = f2bf(u1.z); v[7] = f2bf(u1.w);
        *(bf16x8*)(w16 + i) = v;
    } else {
        const int b = bid - 18;
        if (tid < 192) {
            f32x4 cv = ((const f32x4*)cls)[tid];
            f32x4 pv = ((const f32x4*)pos)[tid];
            ((f32x4*)out)[(size_t)b * (OUTB / 4) + tid] = cv + pv;
        }
    }
}

// ---------------------------------------------------------------------------
// Main: grid 2048, 256 thr (4 waves). bid -> b = bid>>1, eh = bid&1.
// Wave owns 96 embeds: ebase = eh*384 + wave*96 (6 N-tiles of 16).
// A-frag = patch rows (LDS [64][64], XOR-swizzled 16B chunks), B-frag = W (bf16 ws).
// v_mfma_f32_16x16x32_bf16: D lane -> col e (l&15), row n = (l>>4)*4 + reg.
// Per mt tile: pos -> regs FIRST, then ds_reads + 12 MFMA, then unblocked stores.
// ---------------------------------------------------------------------------
__global__ __launch_bounds__(256, 4) void patch_embed_main(const float* __restrict__ x,
                                                           const short* __restrict__ w16,
                                                           const float* __restrict__ pos,
                                                           float* __restrict__ out) {
    __shared__ short A[64 * 64];   // 8 KB

    const int tid  = threadIdx.x;
    const int lane = tid & 63;
    const int wave = tid >> 6;     // 0..3
    const int lr   = lane & 15;
    const int lg   = lane >> 4;    // 0..3
    const int bid  = blockIdx.x;
    const int b    = bid >> 1;
    const int eh   = bid & 1;      // embed half
    const int ebase = eh * 384 + wave * 96;

    // ---- stage x[b] -> LDS bf16 patches [64][64], swizzled 16B chunks ----
    #pragma unroll
    for (int i = 0; i < 2; ++i) {
        const int cid = tid + i * 256;     // 0..511
        const int row = cid >> 3;          // patch n
        const int kb  = cid & 7;
        short* dst = &A[row * 64 + ((kb ^ (row & 7)) * 8)];
        bf16x8 v = {0, 0, 0, 0, 0, 0, 0, 0};
        if (kb < 6) {   // k = c*16 + ph*4 + pw
            const int c   = kb >> 1;
            const int ph0 = (kb & 1) * 2;
            const int gr = row >> 3, gc = row & 7;
            const float* src = x + (size_t)b * 3072 + c * 1024 + (gr * 4 + ph0) * 32 + gc * 4;
            float4 u0 = *(const float4*)src;
            float4 u1 = *(const float4*)(src + 32);
            v[0] = f2bf(u0.x); v[1] = f2bf(u0.y); v[2] = f2bf(u0.z); v[3] = f2bf(u0.w);
            v[4] = f2bf(u1.x); v[5] = f2bf(u1.y); v[6] = f2bf(u1.z); v[7] = f2bf(u1.w);
        }
        *(bf16x8*)dst = v;
    }

    // ---- W fragments (B-operand) from bf16 ws: bw[6][2], no conversion ----
    bf16x8 bw[6][2];
    #pragma unroll
    for (int nt = 0; nt < 6; ++nt) {
        const short* wrow = w16 + (ebase + nt * 16 + lr) * 48;
        bw[nt][0] = *(const bf16x8*)(wrow + lg * 8);           // k = 0..31 slice
        const int k1 = 32 + lg * 8;
        bf16x8 f = {0, 0, 0, 0, 0, 0, 0, 0};
        if (k1 < 48) f = *(const bf16x8*)(wrow + k1);          // 48..63 = K pad
        bw[nt][1] = f;
    }

    __syncthreads();

    // ---- 4 M-tiles, no inter-tile barriers ----
    const size_t outb = (size_t)b * OUTB + EMBED;   // rows n=1..64
    const f32x4 zero = {0.f, 0.f, 0.f, 0.f};
    #pragma unroll 1
    for (int mt = 0; mt < 4; ++mt) {
        // pos prefetch FIRST (24 independent L2 loads; stores won't wait on L2)
        float pv[4][6];
        #pragma unroll
        for (int j = 0; j < 4; ++j) {
            const int n = mt * 16 + lg * 4 + j;
            const float* pr = pos + (size_t)(n + 1) * EMBED + ebase + lr;
            #pragma unroll
            for (int nt = 0; nt < 6; ++nt) pv[j][nt] = pr[nt * 16];
        }

        const int arow = mt * 16 + lr;
        bf16x8 a0 = *(const bf16x8*)&A[arow * 64 + ((lg ^ (arow & 7)) * 8)];         // k 0..31
        bf16x8 a1 = *(const bf16x8*)&A[arow * 64 + (((4 + lg) ^ (arow & 7)) * 8)];   // k 32..63

        f32x4 acc[6];
        #pragma unroll
        for (int nt = 0; nt < 6; ++nt)
            acc[nt] = __builtin_amdgcn_mfma_f32_16x16x32_bf16(a0, bw[nt][0], zero, 0, 0, 0);
        #pragma unroll
        for (int nt = 0; nt < 6; ++nt)
            acc[nt] = __builtin_amdgcn_mfma_f32_16x16x32_bf16(a1, bw[nt][1], acc[nt], 0, 0, 0);

        // stores: D lane -> col (ebase+nt*16+lr), rows n = mt*16 + lg*4 + j
        #pragma unroll
        for (int j = 0; j < 4; ++j) {
            const int n = mt * 16 + lg * 4 + j;
            float* orow = out + outb + (size_t)n * EMBED + ebase + lr;
            #pragma unroll
            for (int nt = 0; nt < 6; ++nt)
                orow[nt * 16] = acc[nt][j] + pv[j][nt];
        }
    }
}

// ---------------------------------------------------------------------------
// d_ws: 36864 bf16 = 73,728 B for converted W.
// ---------------------------------------------------------------------------
extern "C" void kernel_launch(void* const* d_in, const int* in_sizes, int n_in,
                              void* d_out, int out_size, void* d_ws, size_t ws_size,
                              hipStream_t stream) {
    const float* x   = (const float*)d_in[0];
    const float* W   = (const float*)d_in[1];
    const float* cls = (const float*)d_in[2];
    const float* pos = (const float*)d_in[3];
    float* out = (float*)d_out;
    short* w16 = (short*)d_ws;

    hipLaunchKernelGGL(prep_kernel, dim3(18 + BATCH), dim3(256), 0, stream,
                       W, cls, pos, w16, out);
    hipLaunchKernelGGL(patch_embed_main, dim3(BATCH * 2), dim3(256), 0, stream,
                       x, w16, pos, out);
}

// Round 10
// 45.852 us; speedup vs baseline: 1.0401x; 1.0080x over previous
//
#include <hip/hip_runtime.h>

// ViT patch-embed. out[b,0,e]=cls[e]+pos[0,e]; out[b,n+1,e]=sum_k patch[b,n,k]W[e,k]+pos[n+1,e]
// B=1024, 64 patches K=48 (pad 64), E=768. Output 201.3 MB f32 (+3.1 MB cls rows).
// Ledger: R4 NT stores -11.5us. R6 wide-scatter stores -12us. R5/R7/R8/R9
// (scatter, staged-contiguous, 4-per-CU, pos-prefetch) all 46.2-47.7us.
// R10 theory: HBM read/write stream mixing (bus turnaround) caps writes at
// ~4.5 TB/s vs pure-write fill at 6.9 TB/s. Split phases:
//   A: ALL HBM reads (x -> bf16 MFMA-fragment-ordered patches in ws; W cvt; cls).
//   B: pure write stream -- fragment loads from L2/L3-hot ws, no LDS, no
//      barriers, MFMA + store only.

#define BATCH   1024
#define EMBED   768
#define SEQ     65
#define OUTB    (SEQ * EMBED)       // 49920
#define WSPAT   (BATCH * 4096)      // patch frags: 1024 b x 512 chunks x 8 shorts
#define W16OFF  WSPAT               // w16 starts after patches (shorts)

typedef __attribute__((ext_vector_type(8))) short bf16x8;   // 8 bf16 (4 VGPRs)
typedef __attribute__((ext_vector_type(4))) float f32x4;    // MFMA acc / 16B ld-st

__device__ __forceinline__ short f2bf(float f) {
    union { float f; unsigned u; } v; v.f = f;
    unsigned r = v.u + 0x7FFFu + ((v.u >> 16) & 1u);   // RNE
    return (short)(r >> 16);
}

// ---------------------------------------------------------------------------
// Kernel A (read phase).
//  bid < 1024: convert x[b] -> ws patch fragments, MFMA A-frag order.
//    chunk cid (0..511) = (mt*2+kk)*64 + lane, lane=(lg*16+lr):
//      holds row mt*16+lr, k = kk*32+lg*8 .. +7 (bf16x8); kb=kk*4+lg >= 6 -> 0.
//    ws short offset = (b*512 + cid)*8  -> 16B chunks, tid-coalesced.
//  bid in [1024,1042): W (36864 f32) -> bf16 at ws+W16OFF.
//  bid >= 1042: cls row for b = bid-1042 (write-side warmup, only 3.1 MB).
// ---------------------------------------------------------------------------
__global__ __launch_bounds__(256) void prep_kernel(const float* __restrict__ x,
                                                   const float* __restrict__ W,
                                                   const float* __restrict__ cls,
                                                   const float* __restrict__ pos,
                                                   short* __restrict__ ws,
                                                   float* __restrict__ out) {
    const int tid = threadIdx.x;
    const int bid = blockIdx.x;
    if (bid < BATCH) {
        const int b = bid;
        #pragma unroll
        for (int i = 0; i < 2; ++i) {
            const int cid = tid + i * 256;       // 0..511
            const int mt  = cid >> 7;            // 16-patch tile
            const int kk  = (cid >> 6) & 1;      // k-half
            const int lr  = cid & 15;            // fragment row within tile
            const int lg  = (cid >> 4) & 3;      // k-group
            const int kb  = kk * 4 + lg;         // 8-wide k chunk index
            bf16x8 v = {0, 0, 0, 0, 0, 0, 0, 0};
            if (kb < 6) {   // k = c*16 + ph*4 + pw
                const int row = mt * 16 + lr;
                const int c   = kb >> 1;
                const int ph0 = (kb & 1) * 2;
                const int gr = row >> 3, gc = row & 7;
                const float* src = x + (size_t)b * 3072 + c * 1024 + (gr * 4 + ph0) * 32 + gc * 4;
                float4 u0 = *(const float4*)src;
                float4 u1 = *(const float4*)(src + 32);
                v[0] = f2bf(u0.x); v[1] = f2bf(u0.y); v[2] = f2bf(u0.z); v[3] = f2bf(u0.w);
                v[4] = f2bf(u1.x); v[5] = f2bf(u1.y); v[6] = f2bf(u1.z); v[7] = f2bf(u1.w);
            }
            *(bf16x8*)(ws + ((size_t)b * 512 + cid) * 8) = v;
        }
    } else if (bid < BATCH + 18) {
        const int i = ((bid - BATCH) * 256 + tid) * 8;   // f32 index, 8 per thread
        float4 u0 = *(const float4*)(W + i);
        float4 u1 = *(const float4*)(W + i + 4);
        bf16x8 v;
        v[0] = f2bf(u0.x); v[1] = f2bf(u0.y); v[2] = f2bf(u0.z); v[3] = f2bf(u0.w);
        v[4] = f2bf(u1.x); v[5] = f2bf(u1.y); v[6] = f2bf(u1.z); v[7] = f2bf(u1.w);
        *(bf16x8*)(ws + W16OFF + i) = v;
    } else {
        const int b = bid - (BATCH + 18);
        if (tid < 192) {
            f32x4 cv = ((const f32x4*)cls)[tid];
            f32x4 pv = ((const f32x4*)pos)[tid];
            ((f32x4*)out)[(size_t)b * (OUTB / 4) + tid] = cv + pv;
        }
    }
}

// ---------------------------------------------------------------------------
// Kernel B (write phase): grid 2048 x 256 (4 waves), no LDS, no barriers.
// bid -> b = bid>>1, eh = bid&1; wave owns 96 embeds: ebase = eh*384 + wave*96.
// A-frags: coalesced bf16x8 loads from ws (L2/L3-hot). B-frags: w16 (L2-hot).
// v_mfma_f32_16x16x32_bf16: D lane -> col e (l&15), row n = (l>>4)*4 + reg.
// ---------------------------------------------------------------------------
__global__ __launch_bounds__(256) void patch_embed_main(const short* __restrict__ ws,
                                                        const float* __restrict__ pos,
                                                        float* __restrict__ out) {
    const int tid  = threadIdx.x;
    const int lane = tid & 63;
    const int wave = tid >> 6;     // 0..3
    const int lr   = lane & 15;
    const int lg   = lane >> 4;    // 0..3
    const int bid  = blockIdx.x;
    const int b    = bid >> 1;
    const int eh   = bid & 1;
    const int ebase = eh * 384 + wave * 96;

    // ---- W fragments (B-operand) from bf16 ws ----
    const short* w16 = ws + W16OFF;
    bf16x8 bw[6][2];
    #pragma unroll
    for (int nt = 0; nt < 6; ++nt) {
        const short* wrow = w16 + (ebase + nt * 16 + lr) * 48;
        bw[nt][0] = *(const bf16x8*)(wrow + lg * 8);
        const int k1 = 32 + lg * 8;
        bf16x8 f = {0, 0, 0, 0, 0, 0, 0, 0};
        if (k1 < 48) f = *(const bf16x8*)(wrow + k1);   // 48..63 = K pad
        bw[nt][1] = f;
    }

    const short* wsb = ws + (size_t)b * 4096;           // this batch's fragments
    const size_t outb = (size_t)b * OUTB + EMBED;       // rows n=1..64
    const f32x4 zero = {0.f, 0.f, 0.f, 0.f};

    #pragma unroll 1
    for (int mt = 0; mt < 4; ++mt) {
        // fragment loads (L2/L3-hit; 1KB per wave-instr, lane-coalesced)
        bf16x8 a0 = *(const bf16x8*)(wsb + ((mt * 2 + 0) * 64 + lane) * 8);
        bf16x8 a1 = *(const bf16x8*)(wsb + ((mt * 2 + 1) * 64 + lane) * 8);

        // pos prefetch (L2) so stores don't wait on loads
        float pv[4][6];
        #pragma unroll
        for (int j = 0; j < 4; ++j) {
            const float* pr = pos + (size_t)(mt * 16 + lg * 4 + j + 1) * EMBED + ebase + lr;
            #pragma unroll
            for (int nt = 0; nt < 6; ++nt) pv[j][nt] = pr[nt * 16];
        }

        f32x4 acc[6];
        #pragma unroll
        for (int nt = 0; nt < 6; ++nt)
            acc[nt] = __builtin_amdgcn_mfma_f32_16x16x32_bf16(a0, bw[nt][0], zero, 0, 0, 0);
        #pragma unroll
        for (int nt = 0; nt < 6; ++nt)
            acc[nt] = __builtin_amdgcn_mfma_f32_16x16x32_bf16(a1, bw[nt][1], acc[nt], 0, 0, 0);

        // stores: D lane -> col (ebase+nt*16+lr), rows n = mt*16 + lg*4 + j
        #pragma unroll
        for (int j = 0; j < 4; ++j) {
            const int n = mt * 16 + lg * 4 + j;
            float* orow = out + outb + (size_t)n * EMBED + ebase + lr;
            #pragma unroll
            for (int nt = 0; nt < 6; ++nt)
                orow[nt * 16] = acc[nt][j] + pv[j][nt];
        }
    }
}

// ---------------------------------------------------------------------------
// d_ws: 8.39 MB patch frags + 73.7 KB w16 (shorts).
// ---------------------------------------------------------------------------
extern "C" void kernel_launch(void* const* d_in, const int* in_sizes, int n_in,
                              void* d_out, int out_size, void* d_ws, size_t ws_size,
                              hipStream_t stream) {
    const float* x   = (const float*)d_in[0];
    const float* W   = (const float*)d_in[1];
    const float* cls = (const float*)d_in[2];
    const float* pos = (const float*)d_in[3];
    float* out = (float*)d_out;
    short* ws  = (short*)d_ws;

    hipLaunchKernelGGL(prep_kernel, dim3(BATCH + 18 + BATCH), dim3(256), 0, stream,
                       x, W, cls, pos, ws, out);
    hipLaunchKernelGGL(patch_embed_main, dim3(BATCH * 2), dim3(256), 0, stream,
                       ws, pos, out);
}